// Round 14
// baseline (303.720 us; speedup 1.0000x reference)
//
#include <hip/hip_runtime.h>

typedef _Float16 half_t;
typedef __fp16 fp16x2 __attribute__((ext_vector_type(2)));
typedef _Float16 half4 __attribute__((ext_vector_type(4)));
typedef _Float16 half8 __attribute__((ext_vector_type(8)));
typedef float float4v __attribute__((ext_vector_type(4)));

#define MFMA16(a, b, c) __builtin_amdgcn_mfma_f32_16x16x32_f16(a, b, c, 0, 0, 0)

// Hidden-channel storage permutation (swap bits [5:4] <-> [3:2]) so a D-frag
// lane's 16 outputs are contiguous in storage -> b128 epilogue writes.
__device__ __host__ __forceinline__ int sigma_p(int s) {
  return (s & 0xC3) | ((s & 0x0C) << 2) | ((s & 0x30) >> 2);
}

// ReLU + f32->f16 pack via v_cvt_pkrtz (RTZ; <=1 ulp fp16 vs RNE — in budget)
__device__ __forceinline__ half8 relu_pack8(const float4v x, const float4v y) {
  union { fp16x2 h2[4]; half8 h8; } u;
  u.h2[0] = __builtin_amdgcn_cvt_pkrtz(fmaxf(x[0], 0.f), fmaxf(x[1], 0.f));
  u.h2[1] = __builtin_amdgcn_cvt_pkrtz(fmaxf(x[2], 0.f), fmaxf(x[3], 0.f));
  u.h2[2] = __builtin_amdgcn_cvt_pkrtz(fmaxf(y[0], 0.f), fmaxf(y[1], 0.f));
  u.h2[3] = __builtin_amdgcn_cvt_pkrtz(fmaxf(y[2], 0.f), fmaxf(y[3], 0.f));
  return u.h8;
}

// ---------------------------------------------------------------------------
// pack_w0: 18 blocks. w0 -> MFMA frag order with (w9,c) k-reorder (fp16).
// ---------------------------------------------------------------------------
__global__ __launch_bounds__(256) void pack_w0(const float* __restrict__ w0,
                                               half_t* __restrict__ w0p) {
  __shared__ float Wt[32][260];
  const int ks = blockIdx.x;  // 0..17
  const int tid = threadIdx.x;
  {
    const int n4 = (tid & 63) * 4;
    const int kr = tid >> 6;
#pragma unroll
    for (int e = 0; e < 8; e++) {
      const int kp = e * 4 + kr;
      const int kg = ks * 32 + kp;
      const int w9 = kg >> 6, c = kg & 63;
      const int kgo = c * 9 + w9;
      *(float4v*)&Wt[kp][n4] = *(const float4v*)(w0 + (size_t)kgo * 256 + n4);
    }
  }
  __syncthreads();
  const int lane = tid & 63;
  const int l15 = lane & 15;
  const int kq = (lane >> 4) << 3;
#pragma unroll
  for (int e = 0; e < 4; e++) {
    const int nt = e * 4 + (tid >> 6);
    half8 hv;
#pragma unroll
    for (int j = 0; j < 8; j++) hv[j] = (half_t)Wt[kq + j][nt * 16 + l15];
    *(half8*)&w0p[((nt * 18 + ks) * 64 + lane) * 8] = hv;
  }
}

// ---------------------------------------------------------------------------
// conv_l0: blocks 0..511 compute Z = conv3x3(feat,W0)+b0, M=64 positions/block
// (halves per-CU w0p L2 refetch vs M=32). One barrier: halo Ft[di][xi][c]
// staged once; 18 k-chunks read from Ft; weight frags double-buffered.
// Blocks 512..536 pack w1..w4 + w0 tail (consumed only by liif_main).
// ---------------------------------------------------------------------------
__global__ __launch_bounds__(256, 2) void conv_l0(
    const float* __restrict__ feat, const half_t* __restrict__ w0p,
    const float* __restrict__ b0, half_t* __restrict__ Z,
    const float* __restrict__ w1, const float* __restrict__ w2,
    const float* __restrict__ w3, const float* __restrict__ w4,
    const float* __restrict__ w0, half_t* __restrict__ w1p,
    half_t* __restrict__ w2p, half_t* __restrict__ w3p,
    half_t* __restrict__ w4p, half_t* __restrict__ wtp) {
  __shared__ union {
    half_t Ft[3 * 66 * 72];  // [di][xi][c] halves, stride 72 (28512 B)
    float Wt[32][260];
  } sm;
  const int tid = threadIdx.x;
  const int lane = tid & 63, wave = tid >> 6, quad = lane >> 4, l15 = lane & 15;
  const int bid = blockIdx.x;

  if (bid >= 512) {  // ---- weight packing for w1..w4 (+ tail) ----
    const int bb = bid - 494;  // 18..42
    if (bb == 42) {
#pragma unroll
      for (int e = 0; e < 16; e++) {
        const int id = e * 256 + tid;
        const int j = id & 7;
        const int ln = (id >> 3) & 63;
        const int ks = id >> 9;
        const int n = ln & 15;
        const int k = ks * 32 + ((ln >> 4) << 3) + j;
        w4p[id] = (half_t)((n < 3) ? w4[sigma_p(k) * 3 + n] : 0.0f);
      }
#pragma unroll
      for (int e = 0; e < 4; e++)
        wtp[e * 256 + tid] = (half_t)w0[576 * 256 + e * 256 + sigma_p(tid)];
      return;
    }
    const float* w;
    half_t* out;
    int ks;
    if (bb < 26) { w = w1; out = w1p; ks = bb - 18; }
    else if (bb < 34) { w = w2; out = w2p; ks = bb - 26; }
    else { w = w3; out = w3p; ks = bb - 34; }
    {
      const int n4 = (tid & 63) * 4;
      const int kr = tid >> 6;
#pragma unroll
      for (int e = 0; e < 8; e++) {
        const int kp = e * 4 + kr;
        const int kg = sigma_p(ks * 32 + kp);
        *(float4v*)&sm.Wt[kp][n4] = *(const float4v*)(w + (size_t)kg * 256 + n4);
      }
    }
    __syncthreads();
    const int kq = (lane >> 4) << 3;
#pragma unroll
    for (int e = 0; e < 4; e++) {
      const int nt = e * 4 + (tid >> 6);
      half8 hv;
#pragma unroll
      for (int j = 0; j < 8; j++) hv[j] = (half_t)sm.Wt[kq + j][nt * 16 + l15];
      *(half8*)&out[((nt * 8 + ks) * 64 + lane) * 8] = hv;
    }
    return;
  }

  // ---- conv: block covers (b, h, 64-wide x slab) ----
  const int b = bid >> 8;
  const int h = (bid >> 1) & 127;
  const int wbase = (bid & 1) << 6;
  const float* featB = feat + b * (64 * 128 * 128);

  // stage halo: rows r=(di,c) (192), xi 0..65 (x = wbase + xi - 1)
#pragma unroll 8
  for (int it = 0; it < 48; it++) {
    const int idx = it * 256 + tid;
    const int row = idx >> 6;  // 0..191
    const int xi = idx & 63;
    const int di = row >> 6, c = row & 63;
    const int y = h + di - 1;
    const int x = wbase + xi - 1;
    float v = 0.0f;
    if ((unsigned)y < 128u && (unsigned)x < 128u) v = featB[(c << 14) + (y << 7) + x];
    sm.Ft[(di * 66 + xi) * 72 + c] = (half_t)v;
  }
#pragma unroll
  for (int e = 0; e < 2; e++) {  // leftovers xi = 64,65 (384 els)
    const int id2 = e * 256 + tid;
    if (id2 < 384) {
      const int row = id2 >> 1;
      const int xi = 64 + (id2 & 1);
      const int di = row >> 6, c = row & 63;
      const int y = h + di - 1;
      const int x = wbase + xi - 1;
      float v = 0.0f;
      if ((unsigned)y < 128u && (unsigned)x < 128u) v = featB[(c << 14) + (y << 7) + x];
      sm.Ft[(di * 66 + xi) * 72 + c] = (half_t)v;
    }
  }

  half8 bwc[4], bwn[4];
#pragma unroll
  for (int jn = 0; jn < 4; jn++)
    bwc[jn] = *(const half8*)(w0p + ((((wave * 4 + jn) * 18 + 0) * 64 + lane) << 3));
  __syncthreads();  // the ONLY barrier

  const float4v zero4 = {0.0f, 0.0f, 0.0f, 0.0f};
  float4v acc[4][4];
#pragma unroll
  for (int mt = 0; mt < 4; mt++)
#pragma unroll
    for (int jn = 0; jn < 4; jn++) acc[mt][jn] = zero4;

#pragma unroll 1
  for (int ks = 0; ks < 18; ks++) {
    if (ks + 1 < 18) {
#pragma unroll
      for (int jn = 0; jn < 4; jn++)
        bwn[jn] =
            *(const half8*)(w0p + ((((wave * 4 + jn) * 18 + ks + 1) * 64 + lane) << 3));
    }
    const int w9 = ks >> 1;
    const int di = w9 / 3;
    const int dj = w9 - 3 * di;
    const int ch = ((ks & 1) << 5) + quad * 8;
    half8 a[4];
#pragma unroll
    for (int mt = 0; mt < 4; mt++)
      a[mt] = *(const half8*)&sm.Ft[(di * 66 + mt * 16 + l15 + dj) * 72 + ch];
#pragma unroll
    for (int mt = 0; mt < 4; mt++)
#pragma unroll
      for (int jn = 0; jn < 4; jn++)
        acc[mt][jn] = MFMA16(bwc[jn], a[mt], acc[mt][jn]);  // D[n][pos]
#pragma unroll
    for (int jn = 0; jn < 4; jn++) bwc[jn] = bwn[jn];
  }

  // epilogue: S-order -> lane's 16 values contiguous -> 2x 16B global stores
  float4v bb4[4];
#pragma unroll
  for (int jn = 0; jn < 4; jn++)
    bb4[jn] = *(const float4v*)(b0 + (wave * 4 + jn) * 16 + quad * 4);
  const int posbase = b * 16384 + h * 128 + wbase;
#pragma unroll
  for (int mt = 0; mt < 4; mt++) {
    half8 o0, o1;
#pragma unroll
    for (int jn = 0; jn < 2; jn++)
#pragma unroll
      for (int rr = 0; rr < 4; rr++) {
        o0[jn * 4 + rr] = (half_t)(acc[mt][jn][rr] + bb4[jn][rr]);
        o1[jn * 4 + rr] = (half_t)(acc[mt][jn + 2][rr] + bb4[jn + 2][rr]);
      }
    half_t* zp = &Z[(size_t)(posbase + mt * 16 + l15) * 256 + wave * 64 + quad * 16];
    *(half8*)zp = o0;
    *(half8*)(zp + 8) = o1;
  }
}

// ---------------------------------------------------------------------------
// liif_main (verbatim R13, 221 us): M=128 tiles, 2 blocks/CU, Hs stride 280,
// unroll-2 ks-loop, bias-in-acc-init, pkrtz epilogue.
// ---------------------------------------------------------------------------
__global__ __launch_bounds__(256, 2) void liif_main(
    const float* __restrict__ coord, const float* __restrict__ cell,
    const half_t* __restrict__ Zp, const half_t* __restrict__ wtp,
    const half_t* __restrict__ w1p, const half_t* __restrict__ w2p,
    const half_t* __restrict__ w3p, const half_t* __restrict__ w4p,
    const float* __restrict__ b1, const float* __restrict__ b2,
    const float* __restrict__ b3, const float* __restrict__ b4,
    float* __restrict__ outp) {
  __shared__ alignas(16) half_t Hs[128][280];  // 71680 B
  __shared__ int pos4[4][64];
  __shared__ half_t relxh[4][64], relyh[4][64];
  __shared__ half_t cellxh[64], cellyh[64];
  __shared__ float area4[4][64];
  __shared__ float oacc[64][4];

  const int tid = threadIdx.x;
  const int lane = tid & 63;
  const int wave = tid >> 6;
  const int quad = lane >> 4;
  const int l15 = lane & 15;
  const int blk = blockIdx.x;
  const int batch = blk >> 10;

  // ---- geometry ----
  {
    const int t = tid >> 6, row = tid & 63;
    const int gq = blk * 64 + row;
    const float cx0 = coord[gq * 2 + 0], cy0 = coord[gq * 2 + 1];
    const float vx = (t & 2) ? 1.0f : -1.0f;
    const float vy = (t & 1) ? 1.0f : -1.0f;
    const float r = 1.0f / 128.0f, lim = 1.0f - 1e-6f, eps = 1e-6f;
    float cx = fminf(fmaxf(cx0 + vx * r + eps, -lim), lim);
    float cy = fminf(fmaxf(cy0 + vy * r + eps, -lim), lim);
    int ix = (int)floorf((cx + 1.0f) * 64.0f);
    ix = min(max(ix, 0), 127);
    int iy = (int)floorf((cy + 1.0f) * 64.0f);
    iy = min(max(iy, 0), 127);
    float qx = -1.0f + (2.0f * ix + 1.0f) * (1.0f / 128.0f);
    float qy = -1.0f + (2.0f * iy + 1.0f) * (1.0f / 128.0f);
    float rxv = (cx0 - qx) * 128.0f;
    float ryv = (cy0 - qy) * 128.0f;
    pos4[t][row] = (batch << 14) + (ix << 7) + iy;
    relxh[t][row] = (half_t)rxv;
    relyh[t][row] = (half_t)ryv;
    area4[t][row] = fabsf(rxv * ryv) + 1e-9f;
    if (t == 0) {
      cellxh[row] = (half_t)(cell[gq * 2 + 0] * 128.0f);
      cellyh[row] = (half_t)(cell[gq * 2 + 1] * 128.0f);
      oacc[row][0] = 0.0f;
      oacc[row][1] = 0.0f;
      oacc[row][2] = 0.0f;
    }
  }
  __syncthreads();

  const float4v zero4 = {0.0f, 0.0f, 0.0f, 0.0f};
  const half8 zero8 = {0, 0, 0, 0, 0, 0, 0, 0};
  const int c8 = tid & 31;
  const int rbase = (tid >> 5) * 16;

  const half8 wt0 = *(const half8*)(wtp + 0 * 256 + c8 * 8);
  const half8 wt1 = *(const half8*)(wtp + 1 * 256 + c8 * 8);
  const half8 wt2 = *(const half8*)(wtp + 2 * 256 + c8 * 8);
  const half8 wt3 = *(const half8*)(wtp + 3 * 256 + c8 * 8);

  half8 bA[4], bB[4], bf4[2];
#pragma unroll
  for (int jn = 0; jn < 4; jn++)
    bA[jn] = *(const half8*)(w1p + ((((wave * 4 + jn) * 8 + 0) * 64 + lane) << 3));

#pragma unroll 1
  for (int p = 0; p < 2; p++) {
    // ---- gather Z + fp16 rank-4 + ReLU -> Hs ----
#pragma unroll
    for (int e = 0; e < 16; e++) {
      const int r = rbase + e;
      const int corner = 2 * p + (r >> 6);
      const int qrow = r & 63;
      const half8 z = *(const half8*)(Zp + ((size_t)pos4[corner][qrow] << 8) + c8 * 8);
      const half_t rx = relxh[corner][qrow], ry = relyh[corner][qrow];
      const half_t cx = cellxh[qrow], cy = cellyh[qrow];
      const half8 rx8 = {rx, rx, rx, rx, rx, rx, rx, rx};
      const half8 ry8 = {ry, ry, ry, ry, ry, ry, ry, ry};
      const half8 cx8 = {cx, cx, cx, cx, cx, cx, cx, cx};
      const half8 cy8 = {cy, cy, cy, cy, cy, cy, cy, cy};
      half8 v = z + rx8 * wt0 + ry8 * wt1 + cx8 * wt2 + cy8 * wt3;
      v = __builtin_elementwise_max(v, zero8);
      *(half8*)(&Hs[r][c8 * 8]) = v;
    }
    __syncthreads();

    // ---- layers 1..3: M=128, N=256 (4x64 over waves), K=256 (swapped) ----
    float4v acc[8][4];
#pragma unroll 1
    for (int L = 0; L < 3; L++) {
      const half_t* wp = (L == 0) ? w1p : (L == 1) ? w2p : w3p;
      const float* bp = (L == 0) ? b1 : (L == 1) ? b2 : b3;
      float4v bb[4];
#pragma unroll
      for (int jn = 0; jn < 4; jn++)
        bb[jn] = *(const float4v*)(bp + (wave * 4 + jn) * 16 + quad * 4);
#pragma unroll
      for (int mt = 0; mt < 8; mt++)
#pragma unroll
        for (int jn = 0; jn < 4; jn++) acc[mt][jn] = bb[jn];
#pragma unroll 1
      for (int kk = 0; kk < 8; kk += 2) {
#pragma unroll
        for (int jn = 0; jn < 4; jn++)
          bB[jn] =
              *(const half8*)(wp + ((((wave * 4 + jn) * 8 + kk + 1) * 64 + lane) << 3));
        {
          half8 a[8];
#pragma unroll
          for (int mt = 0; mt < 8; mt++)
            a[mt] = *(const half8*)(&Hs[mt * 16 + l15][kk * 32 + quad * 8]);
#pragma unroll
          for (int mt = 0; mt < 8; mt++)
#pragma unroll
            for (int jn = 0; jn < 4; jn++)
              acc[mt][jn] = MFMA16(bA[jn], a[mt], acc[mt][jn]);  // D[n][q]
        }
        if (kk + 2 < 8) {
#pragma unroll
          for (int jn = 0; jn < 4; jn++)
            bA[jn] =
                *(const half8*)(wp + ((((wave * 4 + jn) * 8 + kk + 2) * 64 + lane) << 3));
        }
        {
          half8 a[8];
#pragma unroll
          for (int mt = 0; mt < 8; mt++)
            a[mt] = *(const half8*)(&Hs[mt * 16 + l15][(kk + 1) * 32 + quad * 8]);
#pragma unroll
          for (int mt = 0; mt < 8; mt++)
#pragma unroll
            for (int jn = 0; jn < 4; jn++)
              acc[mt][jn] = MFMA16(bB[jn], a[mt], acc[mt][jn]);
        }
      }
      __syncthreads();  // all waves done READING Hs
      if (L < 2) {
        const half_t* wpn = (L == 0) ? w2p : w3p;
#pragma unroll
        for (int jn = 0; jn < 4; jn++)
          bA[jn] = *(const half8*)(wpn + ((((wave * 4 + jn) * 8 + 0) * 64 + lane) << 3));
      } else {
#pragma unroll
        for (int kx = 0; kx < 2; kx++)
          bf4[kx] = *(const half8*)(w4p + (((wave * 2 + kx) * 64 + lane) << 3));
      }
#pragma unroll
      for (int mt = 0; mt < 8; mt++) {
        const half8 o0 = relu_pack8(acc[mt][0], acc[mt][1]);
        const half8 o1 = relu_pack8(acc[mt][2], acc[mt][3]);
        half_t* hp = &Hs[mt * 16 + l15][wave * 64 + quad * 16];
        *(half8*)hp = o0;
        *(half8*)(hp + 8) = o1;
      }
      __syncthreads();
    }

    // ---- layer 4: 256 -> 3, K split across waves ----
    float4v acc4[8];
#pragma unroll
    for (int mt = 0; mt < 8; mt++) acc4[mt] = zero4;
#pragma unroll
    for (int kx = 0; kx < 2; kx++) {
      const int ks = wave * 2 + kx;
#pragma unroll
      for (int mt = 0; mt < 8; mt++) {
        half8 a = *(const half8*)(&Hs[mt * 16 + l15][ks * 32 + quad * 8]);
        acc4[mt] = MFMA16(a, bf4[kx], acc4[mt]);
      }
    }
    __syncthreads();  // all Hs reads done -> overlay S4 into Hs
    float* S4f = (float*)&Hs[0][0];
    if (l15 < 4) {
#pragma unroll
      for (int mt = 0; mt < 8; mt++)
#pragma unroll
        for (int rr = 0; rr < 4; rr++)
          S4f[((wave * 128 + mt * 16 + quad * 4 + rr) << 2) + l15] = acc4[mt][rr];
    }
    __syncthreads();

    if (p == 0) {
#pragma unroll
      for (int jn = 0; jn < 4; jn++)
        bA[jn] = *(const half8*)(w1p + ((((wave * 4 + jn) * 8 + 0) * 64 + lane) << 3));
    }

    // ---- 2-corner ensemble (diagonal swap: opp = 3 - corner) ----
    if (tid < 192) {
      const int qrow = tid / 3;
      const int j = tid - qrow * 3;
      const int ca = 2 * p, cb = 2 * p + 1;
      float pa = b4[j] + S4f[((0 * 128 + qrow) << 2) + j] +
                 S4f[((1 * 128 + qrow) << 2) + j] + S4f[((2 * 128 + qrow) << 2) + j] +
                 S4f[((3 * 128 + qrow) << 2) + j];
      float pb = b4[j] + S4f[((0 * 128 + 64 + qrow) << 2) + j] +
                 S4f[((1 * 128 + 64 + qrow) << 2) + j] +
                 S4f[((2 * 128 + 64 + qrow) << 2) + j] +
                 S4f[((3 * 128 + 64 + qrow) << 2) + j];
      oacc[qrow][j] += pa * area4[3 - ca][qrow] + pb * area4[3 - cb][qrow];
    }
    __syncthreads();  // S4f region reused as Hs next pass
  }

  if (tid < 192) {
    const int qrow = tid / 3;
    const int j = tid - qrow * 3;
    const float tot =
        area4[0][qrow] + area4[1][qrow] + area4[2][qrow] + area4[3][qrow];
    outp[(blk * 64 + qrow) * 3 + j] = oacc[qrow][j] / tot;
  }
}

// ---------------------------------------------------------------------------
extern "C" void kernel_launch(void* const* d_in, const int* in_sizes, int n_in,
                              void* d_out, int out_size, void* d_ws, size_t ws_size,
                              hipStream_t stream) {
  const float* feat = (const float*)d_in[0];
  const float* coord = (const float*)d_in[1];
  const float* cell = (const float*)d_in[2];
  const float* w0 = (const float*)d_in[3];
  const float* b0 = (const float*)d_in[4];
  const float* w1 = (const float*)d_in[5];
  const float* b1 = (const float*)d_in[6];
  const float* w2 = (const float*)d_in[7];
  const float* b2 = (const float*)d_in[8];
  const float* w3 = (const float*)d_in[9];
  const float* b3 = (const float*)d_in[10];
  const float* w4 = (const float*)d_in[11];
  const float* b4 = (const float*)d_in[12];

  half_t* w0p = (half_t*)d_ws;         // 147456 halves
  half_t* w1p = w0p + 147456;          // 65536
  half_t* w2p = w1p + 65536;
  half_t* w3p = w2p + 65536;
  half_t* w4p = w3p + 65536;           // 4096
  half_t* wtp = w4p + 4096;            // 1024
  half_t* Z = (half_t*)d_ws + 524288;  // [2*16384][256] fp16 (16.8 MB)

  pack_w0<<<18, 256, 0, stream>>>(w0, w0p);
  conv_l0<<<537, 256, 0, stream>>>(feat, w0p, b0, Z, w1, w2, w3, w4, w0, w1p,
                                   w2p, w3p, w4p, wtp);
  liif_main<<<2048, 256, 0, stream>>>(coord, cell, Z, wtp, w1p, w2p, w3p, w4p,
                                      b1, b2, b3, b4, (float*)d_out);
}

// Round 15
// 291.047 us; speedup vs baseline: 1.0435x; 1.0435x over previous
//
#include <hip/hip_runtime.h>

typedef _Float16 half_t;
typedef __fp16 fp16x2 __attribute__((ext_vector_type(2)));
typedef _Float16 half4 __attribute__((ext_vector_type(4)));
typedef _Float16 half8 __attribute__((ext_vector_type(8)));
typedef float float4v __attribute__((ext_vector_type(4)));

#define MFMA16(a, b, c) __builtin_amdgcn_mfma_f32_16x16x32_f16(a, b, c, 0, 0, 0)

// Hidden-channel storage permutation (swap bits [5:4] <-> [3:2]) so a D-frag
// lane's 16 outputs are contiguous in storage -> b128 epilogue writes.
__device__ __host__ __forceinline__ int sigma_p(int s) {
  return (s & 0xC3) | ((s & 0x0C) << 2) | ((s & 0x30) >> 2);
}

// ReLU + f32->f16 pack via v_cvt_pkrtz (RTZ; <=1 ulp fp16 vs RNE — in budget)
__device__ __forceinline__ half8 relu_pack8(const float4v x, const float4v y) {
  union { fp16x2 h2[4]; half8 h8; } u;
  u.h2[0] = __builtin_amdgcn_cvt_pkrtz(fmaxf(x[0], 0.f), fmaxf(x[1], 0.f));
  u.h2[1] = __builtin_amdgcn_cvt_pkrtz(fmaxf(x[2], 0.f), fmaxf(x[3], 0.f));
  u.h2[2] = __builtin_amdgcn_cvt_pkrtz(fmaxf(y[0], 0.f), fmaxf(y[1], 0.f));
  u.h2[3] = __builtin_amdgcn_cvt_pkrtz(fmaxf(y[2], 0.f), fmaxf(y[3], 0.f));
  return u.h8;
}

// ---------------------------------------------------------------------------
// pack_w0: 18 blocks. w0 -> MFMA frag order with (w9,c) k-reorder (fp16).
// ---------------------------------------------------------------------------
__global__ __launch_bounds__(256) void pack_w0(const float* __restrict__ w0,
                                               half_t* __restrict__ w0p) {
  __shared__ float Wt[32][260];
  const int ks = blockIdx.x;  // 0..17
  const int tid = threadIdx.x;
  {
    const int n4 = (tid & 63) * 4;
    const int kr = tid >> 6;
#pragma unroll
    for (int e = 0; e < 8; e++) {
      const int kp = e * 4 + kr;
      const int kg = ks * 32 + kp;
      const int w9 = kg >> 6, c = kg & 63;
      const int kgo = c * 9 + w9;
      *(float4v*)&Wt[kp][n4] = *(const float4v*)(w0 + (size_t)kgo * 256 + n4);
    }
  }
  __syncthreads();
  const int lane = tid & 63;
  const int l15 = lane & 15;
  const int kq = (lane >> 4) << 3;
#pragma unroll
  for (int e = 0; e < 4; e++) {
    const int nt = e * 4 + (tid >> 6);
    half8 hv;
#pragma unroll
    for (int j = 0; j < 8; j++) hv[j] = (half_t)Wt[kq + j][nt * 16 + l15];
    *(half8*)&w0p[((nt * 18 + ks) * 64 + lane) * 8] = hv;
  }
}

// ---------------------------------------------------------------------------
// conv_l0: blocks 0..1023 compute Z = conv3x3(feat,W0)+b0 (M=32 positions,
// 4 blocks/CU for TLP — measured faster than M=64 @2/CU, R14). One barrier:
// halo Ft[di][xi][c] staged once; 18 k-chunks read from Ft; weight frags
// double-buffered in registers. Blocks 1024..1048 pack w1..w4 + w0 tail.
// ---------------------------------------------------------------------------
__global__ __launch_bounds__(256, 4) void conv_l0(
    const float* __restrict__ feat, const half_t* __restrict__ w0p,
    const float* __restrict__ b0, half_t* __restrict__ Z,
    const float* __restrict__ w1, const float* __restrict__ w2,
    const float* __restrict__ w3, const float* __restrict__ w4,
    const float* __restrict__ w0, half_t* __restrict__ w1p,
    half_t* __restrict__ w2p, half_t* __restrict__ w3p,
    half_t* __restrict__ w4p, half_t* __restrict__ wtp) {
  __shared__ union {
    half_t Ft[3 * 34 * 72];  // [di][xi][c] halves, stride 72
    float Wt[32][260];
  } sm;
  const int tid = threadIdx.x;
  const int lane = tid & 63, wave = tid >> 6, quad = lane >> 4, l15 = lane & 15;
  const int bid = blockIdx.x;

  if (bid >= 1024) {  // ---- weight packing for w1..w4 (+ tail) ----
    const int bb = bid - 1006;  // 18..42
    if (bb == 42) {
#pragma unroll
      for (int e = 0; e < 16; e++) {
        const int id = e * 256 + tid;
        const int j = id & 7;
        const int ln = (id >> 3) & 63;
        const int ks = id >> 9;
        const int n = ln & 15;
        const int k = ks * 32 + ((ln >> 4) << 3) + j;
        w4p[id] = (half_t)((n < 3) ? w4[sigma_p(k) * 3 + n] : 0.0f);
      }
#pragma unroll
      for (int e = 0; e < 4; e++)
        wtp[e * 256 + tid] = (half_t)w0[576 * 256 + e * 256 + sigma_p(tid)];
      return;
    }
    const float* w;
    half_t* out;
    int ks;
    if (bb < 26) { w = w1; out = w1p; ks = bb - 18; }
    else if (bb < 34) { w = w2; out = w2p; ks = bb - 26; }
    else { w = w3; out = w3p; ks = bb - 34; }
    {
      const int n4 = (tid & 63) * 4;
      const int kr = tid >> 6;
#pragma unroll
      for (int e = 0; e < 8; e++) {
        const int kp = e * 4 + kr;
        const int kg = sigma_p(ks * 32 + kp);
        *(float4v*)&sm.Wt[kp][n4] = *(const float4v*)(w + (size_t)kg * 256 + n4);
      }
    }
    __syncthreads();
    const int kq = (lane >> 4) << 3;
#pragma unroll
    for (int e = 0; e < 4; e++) {
      const int nt = e * 4 + (tid >> 6);
      half8 hv;
#pragma unroll
      for (int j = 0; j < 8; j++) hv[j] = (half_t)sm.Wt[kq + j][nt * 16 + l15];
      *(half8*)&out[((nt * 8 + ks) * 64 + lane) * 8] = hv;
    }
    return;
  }

  // ---- conv: block covers (b, h, 32-wide x slab) ----
  const int b = bid >> 9;
  const int h = (bid >> 2) & 127;
  const int wbase = (bid & 3) << 5;
  const float* featB = feat + b * (64 * 128 * 128);

  // stage halo: rows r=(di,c) (192), xi 0..33 (x = wbase + xi - 1)
#pragma unroll
  for (int it = 0; it < 24; it++) {
    const int r = it * 8 + wave * 2 + (lane >> 5);
    const int xi = lane & 31;
    const int di = r >> 6, c = r & 63;
    const int y = h + di - 1;
    const int x = wbase + xi - 1;
    float v = 0.0f;
    if ((unsigned)y < 128u && (unsigned)x < 128u) v = featB[(c << 14) + (y << 7) + x];
    sm.Ft[(di * 34 + xi) * 72 + c] = (half_t)v;
  }
#pragma unroll
  for (int e = 0; e < 2; e++) {  // leftovers xi = 32,33
    const int id2 = e * 256 + tid;
    if (id2 < 384) {
      const int r = id2 >> 1;
      const int xi = 32 + (id2 & 1);
      const int di = r >> 6, c = r & 63;
      const int y = h + di - 1;
      const int x = wbase + xi - 1;
      float v = 0.0f;
      if ((unsigned)y < 128u && (unsigned)x < 128u) v = featB[(c << 14) + (y << 7) + x];
      sm.Ft[(di * 34 + xi) * 72 + c] = (half_t)v;
    }
  }

  half8 bwc[4], bwn[4];
#pragma unroll
  for (int jn = 0; jn < 4; jn++)
    bwc[jn] = *(const half8*)(w0p + ((((wave * 4 + jn) * 18 + 0) * 64 + lane) << 3));
  __syncthreads();  // the ONLY barrier

  const float4v zero4 = {0.0f, 0.0f, 0.0f, 0.0f};
  float4v acc[2][4];
#pragma unroll
  for (int mt = 0; mt < 2; mt++)
#pragma unroll
    for (int jn = 0; jn < 4; jn++) acc[mt][jn] = zero4;

#pragma unroll 1
  for (int ks = 0; ks < 18; ks++) {
    if (ks + 1 < 18) {
#pragma unroll
      for (int jn = 0; jn < 4; jn++)
        bwn[jn] =
            *(const half8*)(w0p + ((((wave * 4 + jn) * 18 + ks + 1) * 64 + lane) << 3));
    }
    const int w9 = ks >> 1;
    const int di = w9 / 3;
    const int dj = w9 - 3 * di;
    const int ch = ((ks & 1) << 5) + quad * 8;
    half8 a[2];
#pragma unroll
    for (int mt = 0; mt < 2; mt++)
      a[mt] = *(const half8*)&sm.Ft[(di * 34 + mt * 16 + l15 + dj) * 72 + ch];
#pragma unroll
    for (int mt = 0; mt < 2; mt++)
#pragma unroll
      for (int jn = 0; jn < 4; jn++)
        acc[mt][jn] = MFMA16(bwc[jn], a[mt], acc[mt][jn]);  // D[n][pos]
#pragma unroll
    for (int jn = 0; jn < 4; jn++) bwc[jn] = bwn[jn];
  }

  // epilogue: S-order -> lane's 16 values contiguous -> 2x 16B global stores
  float4v bb4[4];
#pragma unroll
  for (int jn = 0; jn < 4; jn++)
    bb4[jn] = *(const float4v*)(b0 + (wave * 4 + jn) * 16 + quad * 4);
  const int posbase = b * 16384 + h * 128 + wbase;
#pragma unroll
  for (int mt = 0; mt < 2; mt++) {
    half8 o0, o1;
#pragma unroll
    for (int jn = 0; jn < 2; jn++)
#pragma unroll
      for (int rr = 0; rr < 4; rr++) {
        o0[jn * 4 + rr] = (half_t)(acc[mt][jn][rr] + bb4[jn][rr]);
        o1[jn * 4 + rr] = (half_t)(acc[mt][jn + 2][rr] + bb4[jn + 2][rr]);
      }
    half_t* zp = &Z[(size_t)(posbase + mt * 16 + l15) * 256 + wave * 64 + quad * 16];
    *(half8*)zp = o0;
    *(half8*)(zp + 8) = o1;
  }
}

// ---------------------------------------------------------------------------
// liif_main: M=128 tiles (64 q x 2 corners), 2 blocks/CU, Hs stride 280.
// VALU-trimmed: ks-loop unroll-2, bias folded into acc init, pkrtz epilogue.
// ---------------------------------------------------------------------------
__global__ __launch_bounds__(256, 2) void liif_main(
    const float* __restrict__ coord, const float* __restrict__ cell,
    const half_t* __restrict__ Zp, const half_t* __restrict__ wtp,
    const half_t* __restrict__ w1p, const half_t* __restrict__ w2p,
    const half_t* __restrict__ w3p, const half_t* __restrict__ w4p,
    const float* __restrict__ b1, const float* __restrict__ b2,
    const float* __restrict__ b3, const float* __restrict__ b4,
    float* __restrict__ outp) {
  __shared__ alignas(16) half_t Hs[128][280];  // 71680 B
  __shared__ int pos4[4][64];
  __shared__ half_t relxh[4][64], relyh[4][64];
  __shared__ half_t cellxh[64], cellyh[64];
  __shared__ float area4[4][64];
  __shared__ float oacc[64][4];

  const int tid = threadIdx.x;
  const int lane = tid & 63;
  const int wave = tid >> 6;
  const int quad = lane >> 4;
  const int l15 = lane & 15;
  const int blk = blockIdx.x;
  const int batch = blk >> 10;

  // ---- geometry ----
  {
    const int t = tid >> 6, row = tid & 63;
    const int gq = blk * 64 + row;
    const float cx0 = coord[gq * 2 + 0], cy0 = coord[gq * 2 + 1];
    const float vx = (t & 2) ? 1.0f : -1.0f;
    const float vy = (t & 1) ? 1.0f : -1.0f;
    const float r = 1.0f / 128.0f, lim = 1.0f - 1e-6f, eps = 1e-6f;
    float cx = fminf(fmaxf(cx0 + vx * r + eps, -lim), lim);
    float cy = fminf(fmaxf(cy0 + vy * r + eps, -lim), lim);
    int ix = (int)floorf((cx + 1.0f) * 64.0f);
    ix = min(max(ix, 0), 127);
    int iy = (int)floorf((cy + 1.0f) * 64.0f);
    iy = min(max(iy, 0), 127);
    float qx = -1.0f + (2.0f * ix + 1.0f) * (1.0f / 128.0f);
    float qy = -1.0f + (2.0f * iy + 1.0f) * (1.0f / 128.0f);
    float rxv = (cx0 - qx) * 128.0f;
    float ryv = (cy0 - qy) * 128.0f;
    pos4[t][row] = (batch << 14) + (ix << 7) + iy;
    relxh[t][row] = (half_t)rxv;
    relyh[t][row] = (half_t)ryv;
    area4[t][row] = fabsf(rxv * ryv) + 1e-9f;
    if (t == 0) {
      cellxh[row] = (half_t)(cell[gq * 2 + 0] * 128.0f);
      cellyh[row] = (half_t)(cell[gq * 2 + 1] * 128.0f);
      oacc[row][0] = 0.0f;
      oacc[row][1] = 0.0f;
      oacc[row][2] = 0.0f;
    }
  }
  __syncthreads();

  const float4v zero4 = {0.0f, 0.0f, 0.0f, 0.0f};
  const half8 zero8 = {0, 0, 0, 0, 0, 0, 0, 0};
  const int c8 = tid & 31;
  const int rbase = (tid >> 5) * 16;

  const half8 wt0 = *(const half8*)(wtp + 0 * 256 + c8 * 8);
  const half8 wt1 = *(const half8*)(wtp + 1 * 256 + c8 * 8);
  const half8 wt2 = *(const half8*)(wtp + 2 * 256 + c8 * 8);
  const half8 wt3 = *(const half8*)(wtp + 3 * 256 + c8 * 8);

  half8 bA[4], bB[4], bf4[2];
#pragma unroll
  for (int jn = 0; jn < 4; jn++)
    bA[jn] = *(const half8*)(w1p + ((((wave * 4 + jn) * 8 + 0) * 64 + lane) << 3));

#pragma unroll 1
  for (int p = 0; p < 2; p++) {
    // ---- gather Z + fp16 rank-4 + ReLU -> Hs ----
#pragma unroll
    for (int e = 0; e < 16; e++) {
      const int r = rbase + e;
      const int corner = 2 * p + (r >> 6);
      const int qrow = r & 63;
      const half8 z = *(const half8*)(Zp + ((size_t)pos4[corner][qrow] << 8) + c8 * 8);
      const half_t rx = relxh[corner][qrow], ry = relyh[corner][qrow];
      const half_t cx = cellxh[qrow], cy = cellyh[qrow];
      const half8 rx8 = {rx, rx, rx, rx, rx, rx, rx, rx};
      const half8 ry8 = {ry, ry, ry, ry, ry, ry, ry, ry};
      const half8 cx8 = {cx, cx, cx, cx, cx, cx, cx, cx};
      const half8 cy8 = {cy, cy, cy, cy, cy, cy, cy, cy};
      half8 v = z + rx8 * wt0 + ry8 * wt1 + cx8 * wt2 + cy8 * wt3;
      v = __builtin_elementwise_max(v, zero8);
      *(half8*)(&Hs[r][c8 * 8]) = v;
    }
    __syncthreads();

    // ---- layers 1..3: M=128, N=256 (4x64 over waves), K=256 (swapped) ----
    float4v acc[8][4];
#pragma unroll 1
    for (int L = 0; L < 3; L++) {
      const half_t* wp = (L == 0) ? w1p : (L == 1) ? w2p : w3p;
      const float* bp = (L == 0) ? b1 : (L == 1) ? b2 : b3;
      float4v bb[4];
#pragma unroll
      for (int jn = 0; jn < 4; jn++)
        bb[jn] = *(const float4v*)(bp + (wave * 4 + jn) * 16 + quad * 4);
#pragma unroll
      for (int mt = 0; mt < 8; mt++)
#pragma unroll
        for (int jn = 0; jn < 4; jn++) acc[mt][jn] = bb[jn];
#pragma unroll 1
      for (int kk = 0; kk < 8; kk += 2) {
#pragma unroll
        for (int jn = 0; jn < 4; jn++)
          bB[jn] =
              *(const half8*)(wp + ((((wave * 4 + jn) * 8 + kk + 1) * 64 + lane) << 3));
        {
          half8 a[8];
#pragma unroll
          for (int mt = 0; mt < 8; mt++)
            a[mt] = *(const half8*)(&Hs[mt * 16 + l15][kk * 32 + quad * 8]);
#pragma unroll
          for (int mt = 0; mt < 8; mt++)
#pragma unroll
            for (int jn = 0; jn < 4; jn++)
              acc[mt][jn] = MFMA16(bA[jn], a[mt], acc[mt][jn]);  // D[n][q]
        }
        if (kk + 2 < 8) {
#pragma unroll
          for (int jn = 0; jn < 4; jn++)
            bA[jn] =
                *(const half8*)(wp + ((((wave * 4 + jn) * 8 + kk + 2) * 64 + lane) << 3));
        }
        {
          half8 a[8];
#pragma unroll
          for (int mt = 0; mt < 8; mt++)
            a[mt] = *(const half8*)(&Hs[mt * 16 + l15][(kk + 1) * 32 + quad * 8]);
#pragma unroll
          for (int mt = 0; mt < 8; mt++)
#pragma unroll
            for (int jn = 0; jn < 4; jn++)
              acc[mt][jn] = MFMA16(bB[jn], a[mt], acc[mt][jn]);
        }
      }
      __syncthreads();  // all waves done READING Hs
      if (L < 2) {
        const half_t* wpn = (L == 0) ? w2p : w3p;
#pragma unroll
        for (int jn = 0; jn < 4; jn++)
          bA[jn] = *(const half8*)(wpn + ((((wave * 4 + jn) * 8 + 0) * 64 + lane) << 3));
      } else {
#pragma unroll
        for (int kx = 0; kx < 2; kx++)
          bf4[kx] = *(const half8*)(w4p + (((wave * 2 + kx) * 64 + lane) << 3));
      }
#pragma unroll
      for (int mt = 0; mt < 8; mt++) {
        const half8 o0 = relu_pack8(acc[mt][0], acc[mt][1]);
        const half8 o1 = relu_pack8(acc[mt][2], acc[mt][3]);
        half_t* hp = &Hs[mt * 16 + l15][wave * 64 + quad * 16];
        *(half8*)hp = o0;
        *(half8*)(hp + 8) = o1;
      }
      __syncthreads();
    }

    // ---- layer 4: 256 -> 3, K split across waves ----
    float4v acc4[8];
#pragma unroll
    for (int mt = 0; mt < 8; mt++) acc4[mt] = zero4;
#pragma unroll
    for (int kx = 0; kx < 2; kx++) {
      const int ks = wave * 2 + kx;
#pragma unroll
      for (int mt = 0; mt < 8; mt++) {
        half8 a = *(const half8*)(&Hs[mt * 16 + l15][ks * 32 + quad * 8]);
        acc4[mt] = MFMA16(a, bf4[kx], acc4[mt]);
      }
    }
    __syncthreads();  // all Hs reads done -> overlay S4 into Hs
    float* S4f = (float*)&Hs[0][0];
    if (l15 < 4) {
#pragma unroll
      for (int mt = 0; mt < 8; mt++)
#pragma unroll
        for (int rr = 0; rr < 4; rr++)
          S4f[((wave * 128 + mt * 16 + quad * 4 + rr) << 2) + l15] = acc4[mt][rr];
    }
    __syncthreads();

    if (p == 0) {
#pragma unroll
      for (int jn = 0; jn < 4; jn++)
        bA[jn] = *(const half8*)(w1p + ((((wave * 4 + jn) * 8 + 0) * 64 + lane) << 3));
    }

    // ---- 2-corner ensemble (diagonal swap: opp = 3 - corner) ----
    if (tid < 192) {
      const int qrow = tid / 3;
      const int j = tid - qrow * 3;
      const int ca = 2 * p, cb = 2 * p + 1;
      float pa = b4[j] + S4f[((0 * 128 + qrow) << 2) + j] +
                 S4f[((1 * 128 + qrow) << 2) + j] + S4f[((2 * 128 + qrow) << 2) + j] +
                 S4f[((3 * 128 + qrow) << 2) + j];
      float pb = b4[j] + S4f[((0 * 128 + 64 + qrow) << 2) + j] +
                 S4f[((1 * 128 + 64 + qrow) << 2) + j] +
                 S4f[((2 * 128 + 64 + qrow) << 2) + j] +
                 S4f[((3 * 128 + 64 + qrow) << 2) + j];
      oacc[qrow][j] += pa * area4[3 - ca][qrow] + pb * area4[3 - cb][qrow];
    }
    __syncthreads();  // S4f region reused as Hs next pass
  }

  if (tid < 192) {
    const int qrow = tid / 3;
    const int j = tid - qrow * 3;
    const float tot =
        area4[0][qrow] + area4[1][qrow] + area4[2][qrow] + area4[3][qrow];
    outp[(blk * 64 + qrow) * 3 + j] = oacc[qrow][j] / tot;
  }
}

// ---------------------------------------------------------------------------
extern "C" void kernel_launch(void* const* d_in, const int* in_sizes, int n_in,
                              void* d_out, int out_size, void* d_ws, size_t ws_size,
                              hipStream_t stream) {
  const float* feat = (const float*)d_in[0];
  const float* coord = (const float*)d_in[1];
  const float* cell = (const float*)d_in[2];
  const float* w0 = (const float*)d_in[3];
  const float* b0 = (const float*)d_in[4];
  const float* w1 = (const float*)d_in[5];
  const float* b1 = (const float*)d_in[6];
  const float* w2 = (const float*)d_in[7];
  const float* b2 = (const float*)d_in[8];
  const float* w3 = (const float*)d_in[9];
  const float* b3 = (const float*)d_in[10];
  const float* w4 = (const float*)d_in[11];
  const float* b4 = (const float*)d_in[12];

  half_t* w0p = (half_t*)d_ws;         // 147456 halves
  half_t* w1p = w0p + 147456;          // 65536
  half_t* w2p = w1p + 65536;
  half_t* w3p = w2p + 65536;
  half_t* w4p = w3p + 65536;           // 4096
  half_t* wtp = w4p + 4096;            // 1024
  half_t* Z = (half_t*)d_ws + 524288;  // [2*16384][256] fp16 (16.8 MB)

  pack_w0<<<18, 256, 0, stream>>>(w0, w0p);
  conv_l0<<<1049, 256, 0, stream>>>(feat, w0p, b0, Z, w1, w2, w3, w4, w0, w1p,
                                    w2p, w3p, w4p, wtp);
  liif_main<<<2048, 256, 0, stream>>>(coord, cell, Z, wtp, w1p, w2p, w3p, w4p,
                                      b1, b2, b3, b4, (float*)d_out);
}